// Round 1
// 415.588 us; speedup vs baseline: 1.2481x; 1.2481x over previous
//
#include <hip/hip_runtime.h>
#include <hip/hip_fp16.h>
#include <cstdint>
#include <cstring>

// VQR circuit simulator: 16 qubits, B=512, 4 layers.
// CNOTs are GF(2) index-relabeling bookkeeping. Fused 1q gates (SU(2)) are
// XOR-mask pair rotations. Host schedules gates into 2 window passes
// (gen+gates+store, load+gates+measure); within a pass, bundles of 4
// mask-independent gates; each thread applies a bundle on a dim-4 coset
// (16 amps). NEW: amplitudes are fp16 end-to-end (they were already fp16
// between passes); the pair update uses packed v_pk_fma_f16 (2x the f32
// FMA issue rate on CDNA4): np = a*p + b*q, nq = -conj(b)*p + conj(a)*q
// in 8 packed FMAs/pair vs 16 scalar f32 slots. Coefficients are staged
// pre-packed as 4x half2 broadcast pairs [ar,ar][-ai,ai][br,br][-bi,bi];
// runtime parity signs = one 0x80008000 xor on the ai/br regs.

struct BundleMeta {
    uint16_t voff[16];   // coset offsets (local 12-bit index space)
    uint16_t row[4];     // branch parity masks (local bits), per slot
    uint16_t flip[4];    // flip[g] bit t = parity(voff[t] & row[g])
    uint8_t  piv[4];     // pivot bit positions, ASCENDING (rep expansion)
    uint8_t  gidx[4];    // gate coefficient index l*16+w; 0xFF = identity pad
    uint8_t  nl[4];      // branch parity masks over the 4 chunk bits
};

struct PassMeta {
    int       nbundles;
    BundleMeta bd[24];
    uint8_t   gap[4];          // non-local bit positions, ASCENDING (all >=8)
    uint8_t   nlw[4];          // chunk bit k -> wire
    uint8_t   wire_of_bit[12]; // packed LDS bit -> wire (product-state init)
    uint16_t  meas_row;        // measurement parity mask (local bits)
    uint8_t   meas_nl;         // measurement parity mask (chunk bits)
};

typedef _Float16 h2 __attribute__((ext_vector_type(2)));

__device__ __forceinline__ float2 cmul2(float2 a, float2 b) {
    return make_float2(a.x * b.x - a.y * b.y, a.x * b.y + a.y * b.x);
}
__device__ __forceinline__ h2 pkfma(h2 a, h2 b, h2 c) {
    return __builtin_bit_cast(h2, __hfma2(__builtin_bit_cast(__half2, a),
                                          __builtin_bit_cast(__half2, b),
                                          __builtin_bit_cast(__half2, c)));
}
__device__ __forceinline__ h2 h2x(h2 a, unsigned m) {
    return __builtin_bit_cast(h2, __builtin_bit_cast(unsigned, a) ^ m);
}
__device__ __forceinline__ unsigned pkh2(float lo, float hi) {
    h2 v; v.x = (_Float16)lo; v.y = (_Float16)hi;
    return __builtin_bit_cast(unsigned, v);
}

// Fused U = Rz(t2)Ry(t1)Rz(t0)Rx(enc), enc = 2*atan(x).
// Emit packed-h2 quad: [ar,ar] [-ai,ai] [br,br] [-bi,bi].
__global__ __launch_bounds__(512)
void precompute_kernel(const float* __restrict__ X, const float* __restrict__ Wt,
                       const float* __restrict__ Bs, uint4* __restrict__ Ug,
                       float* __restrict__ out)
{
    int id = blockIdx.x * 512 + threadIdx.x;
    if (id >= 512 * 64) return;
    int b = id >> 6, lw = id & 63, l = lw >> 4, w = lw & 15;
    float x  = X[b * 16 + w];
    float ce = 1.0f / sqrtf(1.0f + x * x);
    float se = x * ce;
    float t0 = 0.5f * Wt[(l * 16 + w) * 3 + 0];
    float t1 = 0.5f * Wt[(l * 16 + w) * 3 + 1];
    float t2 = 0.5f * Wt[(l * 16 + w) * 3 + 2];
    float c1 = cosf(t1), s1 = sinf(t1);
    float ca = cosf(t0 + t2), sa = sinf(t0 + t2);
    float cb = cosf(t2 - t0), sb = sinf(t2 - t0);
    float2 W00 = make_float2( c1 * ca, -c1 * sa);
    float2 W01 = make_float2(-s1 * cb,  s1 * sb);
    float2 a  = make_float2(W00.x * ce + W01.y * se, W00.y * ce - W01.x * se);
    float2 bb = make_float2(W00.y * se + W01.x * ce, -W00.x * se + W01.y * ce);
    uint4 o;
    o.x = pkh2( a.x,  a.x);   // A2  = [ar, ar]
    o.y = pkh2(-a.y,  a.y);   // AI2 = [-ai, ai]
    o.z = pkh2(bb.x, bb.x);   // B2  = [br, br]
    o.w = pkh2(-bb.y, bb.y);  // BI2 = [-bi, bi]
    Ug[id] = o;
    if (lw == 0) out[b] = Bs[0];
}

// MODE 0: generate product state + gates + store (fp16)
// MODE 1: load + gates + store (in-place, fp16)
// MODE 2: load + gates + measurement reduce (no store)
template <int MODE>
__global__ __launch_bounds__(256, 6)
void pass_kernel(const uint4* __restrict__ Ug, unsigned* __restrict__ state,
                 float* __restrict__ out, PassMeta meta)
{
    __shared__ __align__(16) h2 amp[4096];   // 16 KiB (one half2 per amp)
    __shared__ uint4 coef[64];               // packed-h2 gate quads (1 KiB)
    const int tid = threadIdx.x;
    const int bb  = blockIdx.x >> 4;
    const unsigned c = blockIdx.x & 15u;
    const size_t base = (size_t)bb << 16;
    if (tid < 64) coef[tid] = Ug[(size_t)bb * 64 + tid];

    auto expand = [&](unsigned x) -> unsigned {   // gaps ascending, all >= 8
        #pragma unroll
        for (int k = 0; k < 4; ++k) {
            unsigned g = meta.gap[k];
            x = ((x >> g) << (g + 1)) | (x & ((1u << g) - 1u)) | (((c >> k) & 1u) << g);
        }
        return x;
    };

    if constexpr (MODE == 0) {
        __syncthreads();   // coef ready
        if (tid == 0) {
            float2 k = make_float2(1.f, 0.f);
            for (int t = 0; t < 4; ++t) {
                uint4 cf = coef[meta.nlw[t]];
                h2 A2  = __builtin_bit_cast(h2, cf.x);
                h2 AI2 = __builtin_bit_cast(h2, cf.y);
                h2 B2  = __builtin_bit_cast(h2, cf.z);
                h2 BI2 = __builtin_bit_cast(h2, cf.w);
                float ar = (float)A2.x, ai = (float)AI2.y;
                float br = (float)B2.x, bi = (float)BI2.y;
                float2 col = ((c >> t) & 1u) ? make_float2(-br, bi)
                                             : make_float2(ar, ai);
                k = cmul2(k, col);
            }
            h2 k2; k2.x = (_Float16)k.x; k2.y = (_Float16)k.y;
            amp[0] = k2;
        }
        __syncthreads();
        for (int s = 0; s < 12; ++s) {
            const int n = 1 << s;
            uint4 cf = coef[meta.wire_of_bit[s]];
            const h2 A2  = __builtin_bit_cast(h2, cf.x);
            const h2 AI2 = __builtin_bit_cast(h2, cf.y);
            const h2 B2  = __builtin_bit_cast(h2, cf.z);
            const h2 BI2 = __builtin_bit_cast(h2, cf.w);
            for (int i = tid; i < n; i += 256) {
                h2 a = amp[i];
                h2 sw = a.yx;
                amp[i + n] = pkfma(-B2, a, BI2 * sw);   // a * (-br, bi)
                amp[i]     = pkfma( A2, a, AI2 * sw);   // a * ( ar, ai)
            }
            __syncthreads();
        }
    } else {
        #pragma unroll
        for (int it = 0; it < 4; ++it) {
            unsigned u = (unsigned)(tid + it * 256) * 4u;
            unsigned a = expand(u);
            uint4 v = *reinterpret_cast<const uint4*>(state + base + a);
            *reinterpret_cast<uint4*>(&amp[u]) = v;   // 4 amps = 16 B, b128
        }
        __syncthreads();   // also covers coef staging
    }

    for (int ci = 0; ci < meta.nbundles; ++ci) {
        const BundleMeta& B = meta.bd[ci];
        unsigned r = (unsigned)tid;
        #pragma unroll
        for (int k = 0; k < 4; ++k) {
            unsigned p = B.piv[k];
            r = ((r >> p) << (p + 1)) | (r & ((1u << p) - 1u));
        }
        const unsigned rb = r << 2;   // byte offset; xor with voff<<2 (scalar)
        h2 a_[16];
        #pragma unroll
        for (int t = 0; t < 16; ++t)
            a_[t] = *(const h2*)((const char*)amp + (rb ^ ((unsigned)B.voff[t] << 2)));
        #pragma unroll
        for (int g = 0; g < 4; ++g) {
            if (B.gidx[g] == 0xFF) continue;       // identity pad (uniform skip)
            const uint4 cf = coef[B.gidx[g]];
            const h2 A2  = __builtin_bit_cast(h2, cf.x);
            const h2 AI0 = __builtin_bit_cast(h2, cf.y);
            const h2 B0  = __builtin_bit_cast(h2, cf.z);
            const h2 BI2 = __builtin_bit_cast(h2, cf.w);
            const unsigned sg = (unsigned)((__popc(r & (unsigned)B.row[g]) +
                                            __popc((unsigned)B.nl[g] & c)) & 1);
            const unsigned gm = (0u - sg) & 0x80008000u;
            const h2 AIg = h2x(AI0, gm);
            const h2 Bg  = h2x(B0,  gm);
            const unsigned fl = B.flip[g];
            #pragma unroll
            for (int t = 0; t < 16; ++t) {
                if (t & (1 << g)) continue;
                const int t2 = t | (1 << g);
                const unsigned fbm = ((fl >> (unsigned)t) & 1u) * 0x80008000u;
                const h2 AIt = h2x(AIg, fbm);      // [-tai, tai]
                const h2 Bt  = h2x(Bg,  fbm);      // [ tbr, tbr]
                const h2 p = a_[t], q = a_[t2];
                // np = alpha*p + beta*q ; alpha=(ar,tai), beta=(tbr,bi)
                h2 u1 = pkfma(A2, p, AIt * p.yx);
                u1 = pkfma(BI2, q.yx, u1);
                // nq = -conj(beta)*p + conj(alpha)*q
                h2 u2 = pkfma(-Bt, p, BI2 * p.yx);
                u2 = pkfma(-AIt, q.yx, u2);
                a_[t]  = pkfma(Bt, q, u1);
                a_[t2] = pkfma(A2, q, u2);
            }
        }
        if (MODE == 2 && ci == meta.nbundles - 1) {
            // measure directly from registers (skip final LDS round-trip)
            float acc = 0.f;
            const unsigned mcp = (unsigned)(__popc((unsigned)meta.meas_nl & c) & 1);
            #pragma unroll
            for (int t = 0; t < 16; ++t) {
                float vr = (float)a_[t].x, vi = (float)a_[t].y;
                float pr = __builtin_fmaf(vr, vr, vi * vi);
                unsigned sg2 = ((unsigned)__popc((r ^ (unsigned)B.voff[t]) &
                               (unsigned)meta.meas_row) & 1u) ^ mcp;
                acc += sg2 ? -pr : pr;
            }
            for (int off = 32; off > 0; off >>= 1) acc += __shfl_down(acc, off, 64);
            if ((tid & 63) == 0) atomicAdd(&out[bb], acc);
            return;
        }
        #pragma unroll
        for (int t = 0; t < 16; ++t)
            *(h2*)((char*)amp + (rb ^ ((unsigned)B.voff[t] << 2))) = a_[t];
        __syncthreads();
    }

    if constexpr (MODE == 2) {
        // fallback (only if nbundles==0): measure from LDS
        float acc = 0.f;
        const unsigned mcp = (unsigned)(__popc((unsigned)meta.meas_nl & c) & 1);
        for (int k = 0; k < 16; ++k) {
            unsigned u = (unsigned)(tid + k * 256);
            h2 a = amp[u];
            float vr = (float)a.x, vi = (float)a.y;
            float pr = __builtin_fmaf(vr, vr, vi * vi);
            acc += (((unsigned)__popc(u & (unsigned)meta.meas_row) & 1u) ^ mcp)
                 ? -pr : pr;
        }
        for (int off = 32; off > 0; off >>= 1) acc += __shfl_down(acc, off, 64);
        if ((tid & 63) == 0) atomicAdd(&out[bb], acc);
    } else {
        #pragma unroll
        for (int it = 0; it < 4; ++it) {
            unsigned u = (unsigned)(tid + it * 256) * 4u;
            unsigned ad = expand(u);
            uint4 v = *reinterpret_cast<const uint4*>(&amp[u]);
            *reinterpret_cast<uint4*>(state + base + ad) = v;
        }
    }
}

extern "C" void kernel_launch(void* const* d_in, const int* in_sizes, int n_in,
                              void* d_out, int out_size, void* d_ws, size_t ws_size,
                              hipStream_t stream)
{
    const float* X  = (const float*)d_in[0];
    const float* Wt = (const float*)d_in[1];
    const float* Bs = (const float*)d_in[2];
    float* out = (float*)d_out;

    const size_t UG_BYTES = (size_t)512 * 64 * sizeof(uint4);  // 512 KiB
    uint4*    Ug    = (uint4*)d_ws;
    unsigned* state = (unsigned*)((char*)d_ws + UG_BYTES);
    size_t avail = ws_size > UG_BYTES ? ws_size - UG_BYTES : 0;
    int group = 1;   // fp16 state: 256 KiB per batch element
    while (group < 512 && (size_t)(group * 2) * 262144ull <= avail)
        group <<= 1;
    const int ngroups = 512 / group;

    // ---- GF(2) bookkeeping (sequential CNOT ring, matches reference) ----
    uint16_t D[16], R[16];
    for (int w = 0; w < 16; ++w) { D[w] = R[w] = (uint16_t)(1u << w); }
    struct G { uint16_t D, R; uint8_t gidx; bool kept; bool sched; };
    G gl[48]; int ng = 0;
    for (int l = 1; l <= 3; ++l) {
        for (int w = 0; w < 16; ++w) { int t = (w + 1) & 15; D[w] ^= D[t]; R[t] ^= R[w]; }
        for (int w = 0; w < 16; ++w)
            gl[ng++] = G{D[w], R[w], (uint8_t)(l * 16 + w), true, false};
    }
    for (int w = 0; w < 16; ++w) { int t = (w + 1) & 15; D[w] ^= D[t]; R[t] ^= R[w]; }
    const uint16_t Rmeas = R[0];

    // Backward prune
    {
        uint16_t keptD[49], keptR[49]; int nk = 0;
        keptD[nk] = 0; keptR[nk] = Rmeas; ++nk;
        for (int i = ng - 1; i >= 0; --i) {
            bool comm = true;
            for (int k = 0; k < nk; ++k) {
                if (__builtin_parity((unsigned)(gl[i].D & keptR[k])) ||
                    __builtin_parity((unsigned)(keptD[k] & gl[i].R))) { comm = false; break; }
            }
            if (comm) gl[i].kept = false;
            else { keptD[nk] = gl[i].D; keptR[nk] = gl[i].R; ++nk; }
        }
    }
    int nkept = 0;
    for (int i = 0; i < ng; ++i) if (gl[i].kept) ++nkept;

    auto commute = [&](int i, int j) -> bool {
        return !(__builtin_parity((unsigned)(gl[i].D & gl[j].R)) ||
                 __builtin_parity((unsigned)(gl[j].D & gl[i].R)));
    };

    const int MAXP = 8;
    auto simulate = [&](uint16_t SA, uint16_t SB, int* passOf) -> int {
        for (int i = 0; i < ng; ++i) gl[i].sched = false;
        int rem = nkept, np = 0, stall = 0;
        while (rem > 0 && np < MAXP) {
            uint16_t S = (np & 1) ? SB : SA;
            int got = 0;
            for (int i = 0; i < ng; ++i) {
                if (!gl[i].kept || gl[i].sched) continue;
                if (gl[i].D & S) continue;
                bool ok = true;
                for (int j = 0; j < i; ++j) {
                    if (!gl[j].kept || gl[j].sched) continue;
                    if (!commute(i, j)) { ok = false; break; }
                }
                if (!ok) continue;
                gl[i].sched = true; --rem; ++got;
                if (passOf) passOf[i] = np;
            }
            ++np;
            if (got == 0) { if (++stall >= 2) break; } else stall = 0;
        }
        return rem == 0 ? np : 99;
    };

    // Window-pair search (LB=12: 4 excluded wires per window, consecutive runs)
    int bestNp = 99, bestA = 0, bestB = 8;
    for (int a = 0; a < 16; ++a) {
        for (int b = 0; b < 16; ++b) {
            uint16_t SA = 0, SB = 0;
            for (int k = 0; k < 4; ++k) {
                SA |= (uint16_t)(1u << ((a + k) & 15));
                SB |= (uint16_t)(1u << ((b + k) & 15));
            }
            int np = simulate(SA, SB, nullptr);
            if (np < bestNp) { bestNp = np; bestA = a; bestB = b; }
        }
    }
    uint16_t SA = 0, SB = 0;
    int exA[4], exB[4];
    for (int k = 0; k < 4; ++k) {
        exA[k] = (bestA + k) & 15; exB[k] = (bestB + k) & 15;
        SA |= (uint16_t)(1u << exA[k]); SB |= (uint16_t)(1u << exB[k]);
    }
    int passOf[48];
    for (int i = 0; i < ng; ++i) passOf[i] = -1;
    int np = simulate(SA, SB, passOf);
    if (np > MAXP) np = MAXP;
    if (np < 2) np = 2;

    // Wire -> bit position: all excluded wires at positions >= 8.
    int wireToPos[16]; bool used[16] = {};
    int pos = 15;
    for (int k = 0; k < 4; ++k) { wireToPos[exA[k]] = pos--; used[exA[k]] = true; }
    for (int k = 0; k < 4; ++k)
        if (!used[exB[k]]) { wireToPos[exB[k]] = pos--; used[exB[k]] = true; }
    for (int w = 0; w < 16; ++w) if (!used[w]) wireToPos[w] = pos--;
    int posToWire[16];
    for (int w = 0; w < 16; ++w) posToWire[wireToPos[w]] = w;

    PassMeta pms[8];
    for (int p = 0; p < np; ++p) {
        PassMeta& M = pms[p];
        memset(&M, 0, sizeof(M));
        const int* ex = (p & 1) ? exB : exA;
        int gp[4], gw[4];
        for (int k = 0; k < 4; ++k) { gp[k] = wireToPos[ex[k]]; gw[k] = ex[k]; }
        for (int a2 = 0; a2 < 4; ++a2)
            for (int b2 = a2 + 1; b2 < 4; ++b2)
                if (gp[b2] < gp[a2]) {
                    int t = gp[a2]; gp[a2] = gp[b2]; gp[b2] = t;
                    t = gw[a2]; gw[a2] = gw[b2]; gw[b2] = t;
                }
        for (int k = 0; k < 4; ++k) { M.gap[k] = (uint8_t)gp[k]; M.nlw[k] = (uint8_t)gw[k]; }
        int packedOfWire[16];
        for (int w = 0; w < 16; ++w) packedOfWire[w] = -1;
        int t = 0;
        for (int q = 0; q < 16; ++q) {
            bool isgap = false;
            for (int k = 0; k < 4; ++k) if (q == gp[k]) isgap = true;
            if (isgap) continue;
            M.wire_of_bit[t] = (uint8_t)posToWire[q];
            packedOfWire[posToWire[q]] = t;
            ++t;
        }
        // local gate list (order preserved from simulate's schedule order)
        struct LG { uint16_t m, r; uint8_t nl, gidx; };
        LG ls[48]; int nsel = 0;
        for (int i = 0; i < ng; ++i) {
            if (!gl[i].kept || passOf[i] != p) continue;
            uint16_t m = 0, r = 0; uint8_t nl = 0;
            for (int w = 0; w < 16; ++w) {
                if ((gl[i].D >> w) & 1) m |= (uint16_t)(1u << packedOfWire[w]);
                if (((gl[i].R >> w) & 1) && packedOfWire[w] >= 0)
                    r |= (uint16_t)(1u << packedOfWire[w]);
            }
            for (int k = 0; k < 4; ++k)
                if ((gl[i].R >> gw[k]) & 1) nl |= (uint8_t)(1u << k);
            ls[nsel++] = LG{m, r, nl, gl[i].gidx};
        }
        // bundle into groups of <=4 with independent masks (consecutive)
        M.nbundles = 0;
        int s = 0;
        while (s < nsel && M.nbundles < 24) {
            BundleMeta& B = M.bd[M.nbundles++];
            for (int j = 0; j < 4; ++j) {
                B.gidx[j] = 0xFF; B.row[j] = 0; B.flip[j] = 0; B.nl[j] = 0;
            }
            uint16_t red[4], om[4]; int pv[4]; int nsl = 0;
            while (nsl < 4 && s < nsel) {
                uint16_t r0 = ls[s].m;
                for (int j = 0; j < nsl; ++j)
                    if ((r0 >> pv[j]) & 1) r0 ^= red[j];
                if (!r0) break;    // dependent -> close bundle
                pv[nsl] = 31 - __builtin_clz((unsigned)r0);
                red[nsl] = r0; om[nsl] = ls[s].m;
                B.gidx[nsl] = ls[s].gidx; B.row[nsl] = ls[s].r; B.nl[nsl] = ls[s].nl;
                ++nsl; ++s;
            }
            for (int b = 11; b >= 0 && nsl < 4; --b) {   // pad basis
                uint16_t r0 = (uint16_t)(1u << b);
                for (int j = 0; j < nsl; ++j)
                    if ((r0 >> pv[j]) & 1) r0 ^= red[j];
                if (!r0) continue;
                pv[nsl] = 31 - __builtin_clz((unsigned)r0);
                red[nsl] = r0; om[nsl] = (uint16_t)(1u << b);
                ++nsl;
            }
            for (int tt = 0; tt < 16; ++tt) {
                uint16_t v = 0;
                for (int j = 0; j < 4; ++j) if ((tt >> j) & 1) v ^= om[j];
                B.voff[tt] = v;
            }
            for (int j = 0; j < 4; ++j) {
                if (B.gidx[j] == 0xFF) continue;
                uint16_t f = 0;
                for (int tt = 0; tt < 16; ++tt)
                    if (__builtin_parity((unsigned)(B.voff[tt] & B.row[j])))
                        f |= (uint16_t)(1u << tt);
                B.flip[j] = f;
            }
            for (int a2 = 0; a2 < 4; ++a2)
                for (int b2 = a2 + 1; b2 < 4; ++b2)
                    if (pv[b2] < pv[a2]) { int tt = pv[a2]; pv[a2] = pv[b2]; pv[b2] = tt; }
            for (int j = 0; j < 4; ++j) B.piv[j] = (uint8_t)pv[j];
        }
        {   // measurement masks (used only if this pass is last)
            uint16_t r = 0; uint8_t nl = 0;
            for (int w = 0; w < 16; ++w)
                if (((Rmeas >> w) & 1) && packedOfWire[w] >= 0)
                    r |= (uint16_t)(1u << packedOfWire[w]);
            for (int k = 0; k < 4; ++k)
                if ((Rmeas >> gw[k]) & 1) nl |= (uint8_t)(1u << k);
            M.meas_row = r; M.meas_nl = nl;
        }
    }

    precompute_kernel<<<dim3(64), dim3(512), 0, stream>>>(X, Wt, Bs, Ug, out);
    for (int g = 0; g < ngroups; ++g) {
        const uint4* ug = Ug + (size_t)g * group * 64;
        float* og = out + (size_t)g * group;
        dim3 grid((unsigned)(group << 4));
        for (int p = 0; p < np; ++p) {
            int mode = (p == 0) ? 0 : ((p == np - 1) ? 2 : 1);
            if (mode == 0)
                pass_kernel<0><<<grid, dim3(256), 0, stream>>>(ug, state, og, pms[p]);
            else if (mode == 1)
                pass_kernel<1><<<grid, dim3(256), 0, stream>>>(ug, state, og, pms[p]);
            else
                pass_kernel<2><<<grid, dim3(256), 0, stream>>>(ug, state, og, pms[p]);
        }
    }

    (void)in_sizes; (void)n_in; (void)out_size; (void)ws_size;
}